// Round 2
// baseline (75.119 us; speedup 1.0000x reference)
//
#include <hip/hip_runtime.h>
#include <stdint.h>

// Problem constants (from reference)
#define BATCH 1024
#define FEAT  784
#define OUTF  1024
#define OR_T  32
#define AND_T 16
#define NIDX  1569          // 1 + 2*FEAT boolean input columns
#define TKDIM 512           // OR_T * AND_T flattened (term,k) extent
#define TK2   256           // packed u16-pairs per output (TKDIM/2)
#define WROW  65            // padded row stride (u32) for widx -> 2-way banks

typedef unsigned long long u64;

// ---------------------------------------------------------------------------
// Single fused kernel. Grid = 256 blocks x 1024 threads; block (g, ob) with
// XCD-swizzled decode keyed on g (2 groups per XCD -> the scattered per-row
// x reads stay L2-hot; per-XCD unique traffic ~2.4 MB).
//
// Phase A (ballot pack): 16 waves cover 196 float4 chunks of the group's 64
//   x rows; __ballot builds each 64-bit column; lbits[0]=ones, [1+f]=x!=0,
//   [785+f]=~(x!=0). 12.8 KB LDS.
// Phase B (weight stage): the block's w slice (64 outputs x 512 tk ints,
//   contiguous 128 KB) is read with perfectly coalesced int4 loads and
//   stored into LDS as u16-packed index pairs widx[tk/2][o] (padded stride
//   65 -> 2-way banks = free on both the staging writes and the eval reads).
// Phase C (eval): thread (tg, o_local) evaluates 2 OR-terms: 16 LDS u32
//   index reads + 32 random ds_read_b64 gathers per thread, AND-chain with
//   or_mask (zor) handling; LDS OR-reduce across 16 waves; 4 coalesced
//   int32 stores.
//
// vs two-kernel version: removes the prep kernel (2.25 waves/CU, latency-
// starved), the inter-kernel bubble, the cross-XCD wt/bits HBM roundtrip,
// and converts eval's 32 global index loads/thread into LDS reads.
// Workspace is unused.
// ---------------------------------------------------------------------------
__global__ __launch_bounds__(1024) void fused2(const float* __restrict__ x,
                                               const int* __restrict__ w,
                                               int* __restrict__ out) {
    __shared__ u64 lbits[1600];                  // 12.8 KB (1569 used)
    __shared__ unsigned int widx[TK2 * WROW];    // 66,560 B
    __shared__ u64 red[1024];                    // 8 KB  (total ~87.5 KB)

    const int bid  = blockIdx.x;
    const int xcd  = bid & 7;
    const int s    = bid >> 3;              // 0..31
    const int g    = xcd * 2 + (s & 1);     // 2 groups per XCD
    const int ob   = s >> 1;                // 0..15
    const int tid  = threadIdx.x;
    const int lane = tid & 63;
    const int wv   = tid >> 6;              // wave 0..15

    // ---- Phase B issue first: coalesced 128 KB w-slice -> LDS u16 pairs ----
    // (issued before the ballot loop so both load streams are in flight)
    const int4* wsrc = (const int4*)(w + (size_t)ob * 64 * TKDIM);
    #pragma unroll
    for (int t = 0; t < 8; ++t) {
        const int q4 = t * 1024 + tid;      // int4 index in slice (0..8191)
        const int4 v = wsrc[q4];
        const int o  = q4 >> 7;             // 128 int4 per output row
        const int tk = (q4 & 127) * 4;      // first of 4 consecutive tk words
        const int r  = tk >> 1;             // packed-pair row (even)
        widx[(r + 0) * WROW + o] =
            ((unsigned int)v.x & 0xFFFFu) | ((unsigned int)v.y << 16);
        widx[(r + 1) * WROW + o] =
            ((unsigned int)v.z & 0xFFFFu) | ((unsigned int)v.w << 16);
    }

    // ---- Phase A: ballot-pack the group's bit columns ----
    const int start = wv * 12 + (wv < 4 ? wv : 4);
    const int cnt   = (wv < 4) ? 13 : 12;
    const float4* xrow = (const float4*)(x + (size_t)(g * 64 + lane) * FEAT);
    for (int i = 0; i < cnt; ++i) {
        const int f4 = start + i;           // covers 0..195 across 16 waves
        const float4 v = xrow[f4];
        const int f = f4 * 4;
        const u64 m0 = __ballot(v.x != 0.0f);
        const u64 m1 = __ballot(v.y != 0.0f);
        const u64 m2 = __ballot(v.z != 0.0f);
        const u64 m3 = __ballot(v.w != 0.0f);
        const u64 mv = (lane == 0) ? m0 : (lane == 1) ? m1 : (lane == 2) ? m2 : m3;
        if (lane < 4) {
            lbits[1 + f + lane]   = mv;
            lbits[785 + f + lane] = ~mv;
        }
    }
    if (tid == 0) lbits[0] = ~0ull;
    __syncthreads();

    // ---- Phase C: evaluate 2 OR-terms per thread ----
    const int o_local = lane;
    const int tg      = wv;

    u64 orv = 0;
    #pragma unroll
    for (int tt = 0; tt < 2; ++tt) {
        const int term = tg * 2 + tt;
        const unsigned int* wrow = widx + (term * 8) * WROW + o_local;
        u64 a = ~0ull;
        unsigned int zor = 0;               // OR of the 16 indices (or_mask)
        #pragma unroll
        for (int kk = 0; kk < 8; ++kk) {
            const unsigned int pk = wrow[kk * WROW];
            zor |= pk;
            a &= lbits[pk & 0xFFFFu];
            a &= lbits[pk >> 16];
        }
        if (zor != 0) orv |= a;             // all-zero term is masked off
    }

    red[tid] = orv;
    __syncthreads();

    u64 full = 0;
    #pragma unroll
    for (int j = 0; j < 16; ++j) full |= red[o_local + j * 64];

    int* outg = out + (size_t)(g * 64) * OUTF + (size_t)ob * 64;
    #pragma unroll
    for (int jj = 0; jj < 4; ++jj) {
        const int j = tg * 4 + jj;
        outg[(size_t)j * OUTF + o_local] = (int)((full >> j) & 1);
    }
}

extern "C" void kernel_launch(void* const* d_in, const int* in_sizes, int n_in,
                              void* d_out, int out_size, void* d_ws, size_t ws_size,
                              hipStream_t stream) {
    (void)in_sizes; (void)n_in; (void)d_ws; (void)ws_size;
    const float* x = (const float*)d_in[0];   // (1024, 784) float32 of 0/1
    const int*   w = (const int*)d_in[1];     // (1024, 32, 16) int32 in [0,1569)
    int* out = (int*)d_out;                   // (1024, 1024) bool -> int32

    fused2<<<256, 1024, 0, stream>>>(x, w, out);
}

// Round 3
// 70.369 us; speedup vs baseline: 1.0675x; 1.0675x over previous
//
#include <hip/hip_runtime.h>
#include <stdint.h>

// Problem constants (from reference)
#define BATCH 1024
#define FEAT  784
#define OUTF  1024
#define OR_T  32
#define AND_T 16
#define NIDX  1569          // 1 + 2*FEAT boolean input columns
#define TKDIM 512           // OR_T * AND_T flattened (term,k) extent
#define TK2   256           // packed u16-pairs per output (TKDIM/2)
#define WROW  65            // padded row stride (u32) for widx -> 2-way banks
#define TROW  17            // padded row stride (u32) for nibble tile

typedef unsigned long long u64;

// ---------------------------------------------------------------------------
// Single fused kernel, v3. Grid = 256 blocks x 1024 threads; block (g, ob),
// XCD swizzle keyed on g (16 same-g blocks land on one XCD -> their shared
// x-slice is L2-resident; the 16x re-read is L2 traffic, not HBM).
//
// Fix vs fused2 (which regressed 64->75 us): fused2's ballot pack read x with
// lane=batch-row (64 cache lines PER wave-instruction; 3.2M L1 transactions
// across the grid). v3 loads x COALESCED (lane walks features: 16 lines per
// instr), packs each float4 into a 4-bit nibble in registers, stores the
// nibble to a padded LDS tile (<=3-way banks), and ballots from the tile
// with lane=row (2-way, free). 13 double-buffered 64-feature chunks; next
// chunk's global load is issued before the current chunk's ballots.
//
// Phase W (unchanged from fused2, verified): stage the block's w slice
//   (64 outputs x 512 tk ints, contiguous 128 KB, coalesced int4) into LDS
//   as u16-packed index pairs widx[tk/2][o], padded stride 65.
// Phase E (unchanged): thread (tg, o_local) evaluates 2 OR-terms: 16 LDS u32
//   index reads + 32 random ds_read_b64 gathers, or_mask (zor) handling;
//   LDS OR-reduce across 16 waves; 4 coalesced int32 stores.
// ---------------------------------------------------------------------------
__global__ __launch_bounds__(1024) void fused3(const float* __restrict__ x,
                                               const int* __restrict__ w,
                                               int* __restrict__ out) {
    __shared__ u64 lbits[1600];                    // 12.8 KB (1569 used)
    __shared__ unsigned int widx[TK2 * WROW];      // 66,560 B
    __shared__ u64 red[1024];                      // 8 KB
    __shared__ unsigned int tile[2][64 * TROW];    // 8.7 KB  (total ~96.3 KB)

    const int bid  = blockIdx.x;
    const int xcd  = bid & 7;
    const int s    = bid >> 3;              // 0..31
    const int g    = xcd * 2 + (s & 1);     // 2 groups per XCD
    const int ob   = s >> 1;                // 0..15
    const int tid  = threadIdx.x;
    const int lane = tid & 63;
    const int wv   = tid >> 6;              // wave 0..15

    const float* xg = x + (size_t)(g * 64) * FEAT;

    // ---- chunk-0 x load (coalesced: 64 rows x 16 float4) ----
    {
        const int r = tid >> 4;             // row 0..63
        const int q = tid & 15;             // float4 col 0..15
        const float4 v = *(const float4*)(xg + (size_t)r * FEAT + q * 4);
        const unsigned int nib = (v.x != 0.0f ? 1u : 0u)
                               | (v.y != 0.0f ? 2u : 0u)
                               | (v.z != 0.0f ? 4u : 0u)
                               | (v.w != 0.0f ? 8u : 0u);
        tile[0][r * TROW + q] = nib;
    }

    // ---- Phase W: stage w slice -> widx (independent of x path) ----
    const int4* wsrc = (const int4*)(w + (size_t)ob * 64 * TKDIM);
    #pragma unroll
    for (int t = 0; t < 8; ++t) {
        const int q4 = t * 1024 + tid;      // int4 index in slice (0..8191)
        const int4 v = wsrc[q4];
        const int o  = q4 >> 7;             // 128 int4 per output row
        const int rr = (q4 & 127) * 2;      // packed-pair row (even)
        widx[(rr + 0) * WROW + o] =
            ((unsigned int)v.x & 0xFFFFu) | ((unsigned int)v.y << 16);
        widx[(rr + 1) * WROW + o] =
            ((unsigned int)v.z & 0xFFFFu) | ((unsigned int)v.w << 16);
    }
    if (tid == 0) lbits[0] = ~0ull;
    __syncthreads();

    // ---- 13 chunks: ballot tile[i&1] while loading chunk i+1 ----
    for (int i = 0; i < 13; ++i) {
        // issue next chunk's load first (latency hides under ballots)
        unsigned int nib = 0;
        int r = 0, q = 0;
        bool st = false;
        if (i < 12) {
            const int ii = i + 1;
            if (ii < 12) {                  // full 64-feature chunk
                r = tid >> 4; q = tid & 15; st = true;
                const float4 v = *(const float4*)(xg + (size_t)r * FEAT
                                                  + ii * 64 + q * 4);
                nib = (v.x != 0.0f ? 1u : 0u) | (v.y != 0.0f ? 2u : 0u)
                    | (v.z != 0.0f ? 4u : 0u) | (v.w != 0.0f ? 8u : 0u);
            } else if (tid < 256) {         // chunk 12: 16 features
                r = tid >> 2; q = tid & 3; st = true;
                const float4 v = *(const float4*)(xg + (size_t)r * FEAT
                                                  + 768 + q * 4);
                nib = (v.x != 0.0f ? 1u : 0u) | (v.y != 0.0f ? 2u : 0u)
                    | (v.z != 0.0f ? 4u : 0u) | (v.w != 0.0f ? 8u : 0u);
            }
        }

        // ballot current chunk from tile[i&1]; wave wv owns nibble column wv
        const int nq = (i < 12) ? 16 : 4;   // valid columns this chunk
        if (wv < nq) {
            const unsigned int vr = tile[i & 1][lane * TROW + wv];
            #pragma unroll
            for (int j = 0; j < 4; ++j) {
                const u64 m = __ballot(((vr >> j) & 1u) != 0u);
                const int f = i * 64 + wv * 4 + j;
                if (lane < 2)
                    lbits[(lane ? 785 : 1) + f] = lane ? ~m : m;
            }
        }

        if (st) tile[(i + 1) & 1][r * TROW + q] = nib;
        __syncthreads();
    }

    // ---- Phase E: evaluate 2 OR-terms per thread (verified in fused2) ----
    const int o_local = lane;
    const int tg      = wv;

    u64 orv = 0;
    #pragma unroll
    for (int tt = 0; tt < 2; ++tt) {
        const int term = tg * 2 + tt;
        const unsigned int* wrow = widx + (term * 8) * WROW + o_local;
        u64 a = ~0ull;
        unsigned int zor = 0;               // OR of the 16 indices (or_mask)
        #pragma unroll
        for (int kk = 0; kk < 8; ++kk) {
            const unsigned int pk = wrow[kk * WROW];
            zor |= pk;
            a &= lbits[pk & 0xFFFFu];
            a &= lbits[pk >> 16];
        }
        if (zor != 0) orv |= a;             // all-zero term is masked off
    }

    red[tid] = orv;
    __syncthreads();

    u64 full = 0;
    #pragma unroll
    for (int j = 0; j < 16; ++j) full |= red[o_local + j * 64];

    int* outg = out + (size_t)(g * 64) * OUTF + (size_t)ob * 64;
    #pragma unroll
    for (int jj = 0; jj < 4; ++jj) {
        const int j = tg * 4 + jj;
        outg[(size_t)j * OUTF + o_local] = (int)((full >> j) & 1);
    }
}

extern "C" void kernel_launch(void* const* d_in, const int* in_sizes, int n_in,
                              void* d_out, int out_size, void* d_ws, size_t ws_size,
                              hipStream_t stream) {
    (void)in_sizes; (void)n_in; (void)d_ws; (void)ws_size;
    const float* x = (const float*)d_in[0];   // (1024, 784) float32 of 0/1
    const int*   w = (const int*)d_in[1];     // (1024, 32, 16) int32 in [0,1569)
    int* out = (int*)d_out;                   // (1024, 1024) bool -> int32

    fused3<<<256, 1024, 0, stream>>>(x, w, out);
}

// Round 4
// 64.686 us; speedup vs baseline: 1.1613x; 1.0878x over previous
//
#include <hip/hip_runtime.h>
#include <stdint.h>

// Problem constants (from reference)
#define BATCH 1024
#define FEAT  784
#define OUTF  1024
#define OR_T  32
#define AND_T 16
#define NIDX  1569          // 1 + 2*FEAT boolean input columns
#define BSTRIDE 1600        // padded u64 words per batch-group bit column
#define NGROUP  16          // BATCH / 64
#define TKDIM   512         // OR_T * AND_T flattened (term,k) extent

// ws layout
#define BITS_BYTES (NGROUP * BSTRIDE * 8)     // 204,800
#define WT_OFF     208896                     // 4 KB-aligned
#define WS_NEED    (WT_OFF + (size_t)TKDIM * OUTF * 4)   // ~2.3 MB

#define NB_PACK 448                           // 16 groups x 28 f-slices
#define NB_TR   128                           // (1024/64) x (512/64)

typedef unsigned long long u64;
typedef __attribute__((ext_vector_type(2))) u64 u64x2;   // 16B

// ---------------------------------------------------------------------------
// Prep kernel — byte-identical to the verified 64.3 us baseline.
//  blocks [0,448): pack bit columns (ballot transpose of x).
//  blocks [448,576): transpose w (1024x512) -> wt[tk*1024+o] via LDS tile.
// ---------------------------------------------------------------------------
__global__ __launch_bounds__(64) void prep(const float* __restrict__ x,
                                           const int* __restrict__ w,
                                           u64* __restrict__ bits,
                                           int* __restrict__ wt) {
    __shared__ int t2[64 * 65];
    const int b   = blockIdx.x;
    const int tid = threadIdx.x;

    if (b < NB_PACK) {
        const int g  = b / 28;
        const int fb = b % 28;
        const float4* xrow = (const float4*)(x + (size_t)(g * 64 + tid) * FEAT);
        u64* bg = bits + (size_t)g * BSTRIDE;

        #pragma unroll
        for (int i = 0; i < 7; ++i) {       // 28 slices * 7 * 4 = 784 features
            const int f4 = fb * 7 + i;
            const float4 v = xrow[f4];
            const int f = f4 * 4;
            const u64 m0 = __ballot(v.x != 0.0f);
            const u64 m1 = __ballot(v.y != 0.0f);
            const u64 m2 = __ballot(v.z != 0.0f);
            const u64 m3 = __ballot(v.w != 0.0f);
            const u64 mv = (tid == 0) ? m0 : (tid == 1) ? m1 : (tid == 2) ? m2 : m3;
            if (tid < 4) {
                bg[1 + f + tid]   = mv;
                bg[785 + f + tid] = ~mv;
            }
        }
        if (fb == 0 && tid == 0) bg[0] = ~0ull;
    } else {
        const int b2     = b - NB_PACK;
        const int o_base  = (b2 & 15) * 64;
        const int tk_base = (b2 >> 4) * 64;

        #pragma unroll
        for (int i = 0; i < 16; ++i) {      // load 64(o) x 64(tk) tile
            const int idx = i * 64 + tid;
            const int r = idx >> 4;         // o row 0..63
            const int q = idx & 15;         // tk int4 index
            const int4 v = *(const int4*)(w + (size_t)(o_base + r) * TKDIM
                                            + tk_base + q * 4);
            t2[(q * 4 + 0) * 65 + r] = v.x;
            t2[(q * 4 + 1) * 65 + r] = v.y;
            t2[(q * 4 + 2) * 65 + r] = v.z;
            t2[(q * 4 + 3) * 65 + r] = v.w;
        }
        __syncthreads();
        #pragma unroll
        for (int i = 0; i < 16; ++i) {      // store transposed, coalesced
            const int idx = i * 64 + tid;
            const int rr = idx >> 4;        // tk row 0..63
            const int qq = idx & 15;        // o int4 index
            int4 o4;
            o4.x = t2[rr * 65 + qq * 4 + 0];
            o4.y = t2[rr * 65 + qq * 4 + 1];
            o4.z = t2[rr * 65 + qq * 4 + 2];
            o4.w = t2[rr * 65 + qq * 4 + 3];
            *(int4*)(wt + (size_t)(tk_base + rr) * OUTF + o_base + qq * 4) = o4;
        }
    }
}

// ---------------------------------------------------------------------------
// Eval kernel v2: 1024 blocks x 256 threads (4 blocks/CU, 16 waves) instead
// of 256 x 1024 (1 block/CU). Same per-CU gather/wt work; cross-block TLP
// now hides staging latency, the barrier, and the LDS gather chains.
// Block (g, ob, q): 16 outputs o = ob*64 + q*16 + (tid&15); thread (tg,
// o_local) evaluates 2 OR-terms; LDS OR-reduce over 16 term-groups;
// 4 coalesced int32 stores per thread. XCD swizzle: each XCD sees ob in
// {xcd, xcd+8} only -> its 2x128 KB wt slices stay L2-hot.
// ---------------------------------------------------------------------------
__global__ __launch_bounds__(256) void eval3(const int* __restrict__ wt,
                                             const u64* __restrict__ bits,
                                             int* __restrict__ out) {
    __shared__ u64 lbits[BSTRIDE];   // 12.8 KB
    __shared__ u64 red[256];         // 2 KB

    const int bid = blockIdx.x;
    const int xcd = bid & 7;
    const int s   = bid >> 3;              // 0..127
    const int ob  = xcd + 8 * (s & 1);     // 0..15, 2 per XCD
    const int q   = (s >> 1) & 3;          // quarter 0..3
    const int g   = s >> 3;                // 0..15
    const int tid = threadIdx.x;

    // Stage bit table: 800 x 16B with b128 copies, 256-thread strided.
    const u64* bg = bits + (size_t)g * BSTRIDE;
    #pragma unroll
    for (int i = 0; i < 4; ++i) {
        const int t = i * 256 + tid;
        if (t < BSTRIDE / 2) {
            ((u64x2*)lbits)[t] = ((const u64x2*)bg)[t];
        }
    }
    __syncthreads();

    const int o_local = tid & 15;
    const int tg      = tid >> 4;          // term-group 0..15
    const int o       = ob * 64 + q * 16 + o_local;

    u64 orv = 0;
    #pragma unroll
    for (int tt = 0; tt < 2; ++tt) {
        const int term = tg * 2 + tt;
        const int* wcol = wt + (size_t)(term * AND_T) * OUTF + o;
        u64 a = ~0ull;
        int zor = 0;                        // OR of the 16 indices (or_mask)
        #pragma unroll
        for (int k = 0; k < 16; ++k) {
            const int idx = wcol[(size_t)k * OUTF];
            zor |= idx;
            a &= lbits[idx];
        }
        if (zor != 0) orv |= a;             // all-zero term is masked off
    }

    red[tid] = orv;
    __syncthreads();

    u64 full = 0;
    #pragma unroll
    for (int j = 0; j < 16; ++j) full |= red[j * 16 + o_local];

    int* outg = out + (size_t)(g * 64) * OUTF + (size_t)ob * 64 + q * 16;
    #pragma unroll
    for (int jj = 0; jj < 4; ++jj) {
        const int j = tg * 4 + jj;
        outg[(size_t)j * OUTF + o_local] = (int)((full >> j) & 1);
    }
}

// ---------------------------------------------------------------------------
// Fallback: fully fused if ws is too small. Same math (verified baseline).
// ---------------------------------------------------------------------------
__global__ __launch_bounds__(1024) void binlayer_fused(const float* __restrict__ x,
                                                       const int* __restrict__ w,
                                                       int* __restrict__ out) {
    __shared__ u64 lbits[BSTRIDE];
    __shared__ u64 red[1024];

    const int g    = blockIdx.x;
    const int ob   = blockIdx.y;
    const int tid  = threadIdx.x;
    const int lane = tid & 63;
    const int wv   = tid >> 6;

    const int start = wv * 12 + (wv < 4 ? wv : 4);
    const int cnt   = (wv < 4) ? 13 : 12;
    const float4* xrow = (const float4*)(x + (size_t)(g * 64 + lane) * FEAT);
    for (int i = 0; i < cnt; ++i) {
        const int f4 = start + i;
        const float4 v = xrow[f4];
        const int f = f4 * 4;
        const u64 m0 = __ballot(v.x != 0.0f);
        const u64 m1 = __ballot(v.y != 0.0f);
        const u64 m2 = __ballot(v.z != 0.0f);
        const u64 m3 = __ballot(v.w != 0.0f);
        const u64 mv = (lane == 0) ? m0 : (lane == 1) ? m1 : (lane == 2) ? m2 : m3;
        if (lane < 4) {
            lbits[1 + f + lane]   = mv;
            lbits[785 + f + lane] = ~mv;
        }
    }
    if (tid == 0) lbits[0] = ~0ull;
    __syncthreads();

    const int o_local = tid & 63;
    const int tg      = tid >> 6;
    const int o       = ob * 64 + o_local;
    const int4* wq = (const int4*)(w + ((size_t)o * OR_T + tg * 2) * AND_T);

    u64 orv = 0;
    #pragma unroll
    for (int tt = 0; tt < 2; ++tt) {
        u64 a = ~0ull;
        int zor = 0;
        #pragma unroll
        for (int k = 0; k < 4; ++k) {
            const int4 wi = wq[tt * 4 + k];
            zor |= wi.x | wi.y | wi.z | wi.w;
            a &= lbits[wi.x];
            a &= lbits[wi.y];
            a &= lbits[wi.z];
            a &= lbits[wi.w];
        }
        if (zor != 0) orv |= a;
    }

    red[tid] = orv;
    __syncthreads();

    u64 full = 0;
    #pragma unroll
    for (int j = 0; j < 16; ++j) full |= red[o_local + j * 64];

    int* outg = out + (size_t)(g * 64) * OUTF + (size_t)ob * 64;
    #pragma unroll
    for (int jj = 0; jj < 4; ++jj) {
        const int j = tg * 4 + jj;
        outg[(size_t)j * OUTF + o_local] = (int)((full >> j) & 1);
    }
}

extern "C" void kernel_launch(void* const* d_in, const int* in_sizes, int n_in,
                              void* d_out, int out_size, void* d_ws, size_t ws_size,
                              hipStream_t stream) {
    const float* x = (const float*)d_in[0];   // (1024, 784) float32 of 0/1
    const int*   w = (const int*)d_in[1];     // (1024, 32, 16) int32 in [0,1569)
    int* out = (int*)d_out;                   // (1024, 1024) bool -> int32

    if (ws_size >= WS_NEED) {
        u64* bits = (u64*)d_ws;
        int* wt   = (int*)((char*)d_ws + WT_OFF);
        prep<<<NB_PACK + NB_TR, 64, 0, stream>>>(x, w, bits, wt);
        eval3<<<1024, 256, 0, stream>>>(wt, bits, out);
    } else {
        binlayer_fused<<<dim3(NGROUP, OUTF / 64), 1024, 0, stream>>>(x, w, out);
    }
}